// Round 16
// baseline (1168.543 us; speedup 1.0000x reference)
//
#include <hip/hip_runtime.h>
#include <hip/hip_bf16.h>
#include <math.h>

#define Bb 2
#define Ss 2048
#define Ee 1024
#define Hh 16
#define Oo 32
#define Cc 2
#define EPSf 1e-5f
#define NSEG 64
#define SEGL 32
#define NGRP 8
#define GRPL 8

typedef __hip_bfloat16 bf16;
typedef __attribute__((ext_vector_type(8))) short short8;
typedef __attribute__((ext_vector_type(4))) float f32x4;

// ---------------- LayerNorm (standard layout; LN2) ----------------
template <typename OT>
__global__ __launch_bounds__(256) void ln_kernel(const float* __restrict__ x,
                                                 const float* __restrict__ g,
                                                 OT* __restrict__ out) {
    __shared__ float red[8];
    int row = blockIdx.x;
    const float4* xr = (const float4*)(x + (size_t)row * Ee);
    float4 v = xr[threadIdx.x];
    float s = v.x + v.y + v.z + v.w;
#pragma unroll
    for (int off = 32; off > 0; off >>= 1) s += __shfl_xor(s, off);
    int wave = threadIdx.x >> 6, lane = threadIdx.x & 63;
    if (!lane) red[wave] = s;
    __syncthreads();
    float mu = (red[0] + red[1] + red[2] + red[3]) * (1.0f / Ee);
    float dx = v.x - mu, dy = v.y - mu, dz = v.z - mu, dw = v.w - mu;
    float sq = dx * dx + dy * dy + dz * dz + dw * dw;
#pragma unroll
    for (int off = 32; off > 0; off >>= 1) sq += __shfl_xor(sq, off);
    if (!lane) red[wave + 4] = sq;
    __syncthreads();
    float var = (red[4] + red[5] + red[6] + red[7]) * (1.0f / Ee);
    float rs = rsqrtf(var + EPSf);
    float4 gv = ((const float4*)g)[threadIdx.x];
    float o0 = dx * rs * gv.x, o1 = dy * rs * gv.y, o2 = dz * rs * gv.z, o3 = dw * rs * gv.w;
    if constexpr (sizeof(OT) == 4) {
        ((float4*)((float*)out + (size_t)row * Ee))[threadIdx.x] = make_float4(o0, o1, o2, o3);
    } else {
        __align__(8) bf16 t[4] = {__float2bfloat16(o0), __float2bfloat16(o1),
                                  __float2bfloat16(o2), __float2bfloat16(o3)};
        ((ushort4*)((unsigned short*)out + (size_t)row * Ee))[threadIdx.x] = *(const ushort4*)t;
    }
}

// ---------------- fused prep: LN1 (chain-major out) + weight f2bf conversions ----------------
__device__ __forceinline__ void cvt4(const float* in, bf16* out, int i) {
    float4 v = ((const float4*)in)[i];
    __align__(8) bf16 t[4] = {__float2bfloat16(v.x), __float2bfloat16(v.y),
                              __float2bfloat16(v.z), __float2bfloat16(v.w)};
    ((ushort4*)out)[i] = *(const ushort4*)t;
}

__global__ __launch_bounds__(256) void prep_kernel(const float* __restrict__ act,
                                                   const float* __restrict__ g,
                                                   float* __restrict__ hs,
                                                   const float* __restrict__ wa, bf16* __restrict__ oa,
                                                   const float* __restrict__ wb, bf16* __restrict__ ob,
                                                   const float* __restrict__ wc, bf16* __restrict__ oc) {
    int bid = blockIdx.x;
    if (bid < Bb * Ss) {
        __shared__ float red[8];
        int row = bid;
        const float4* xr = (const float4*)(act + (size_t)row * Ee);
        float4 v = xr[threadIdx.x];
        float s = v.x + v.y + v.z + v.w;
#pragma unroll
        for (int off = 32; off > 0; off >>= 1) s += __shfl_xor(s, off);
        int wave = threadIdx.x >> 6, lane = threadIdx.x & 63;
        if (!lane) red[wave] = s;
        __syncthreads();
        float mu = (red[0] + red[1] + red[2] + red[3]) * (1.0f / Ee);
        float dx = v.x - mu, dy = v.y - mu, dz = v.z - mu, dw = v.w - mu;
        float sq = dx * dx + dy * dy + dz * dz + dw * dw;
#pragma unroll
        for (int off = 32; off > 0; off >>= 1) sq += __shfl_xor(sq, off);
        if (!lane) red[wave + 4] = sq;
        __syncthreads();
        float var = (red[4] + red[5] + red[6] + red[7]) * (1.0f / Ee);
        float rs = rsqrtf(var + EPSf);
        float4 gv = ((const float4*)g)[threadIdx.x];
        float o0 = dx * rs * gv.x, o1 = dy * rs * gv.y, o2 = dz * rs * gv.z, o3 = dw * rs * gv.w;
        int b = row >> 11, t = row & 2047;
        int e0 = threadIdx.x * 4;
        int head = e0 >> 6;
        float* dst = hs + (((size_t)(b * Hh + head) * Ss) + t) * 64 + (e0 & 63);
        *(float4*)dst = make_float4(o0, o1, o2, o3);
    } else {
        int i = (bid - Bb * Ss) * 256 + threadIdx.x;
        const int nA = (1024 * 1024) / 4;
        const int nB = (4 * 1024 * 1024) / 4;
        if (i < nA) cvt4(wa, oa, i);
        else if (i < nA + nB) cvt4(wb, ob, i - nA);
        else cvt4(wc, oc, i - nA - nB);
    }
}

// ======================= Fused segmented scan: one block per chain =======================
__device__ __forceinline__ void row_matmul(float e[32], const float* __restrict__ T) {
    float r[32];
#pragma unroll
    for (int q = 0; q < 32; ++q) r[q] = 0.f;
#pragma unroll
    for (int kk = 0; kk < 32; ++kk) {
        float ekk = e[kk];
        const float4* tr = (const float4*)(T + kk * 32);
#pragma unroll
        for (int j = 0; j < 8; ++j) {
            float4 tv = tr[j];
            r[4 * j + 0] = fmaf(ekk, tv.x, r[4 * j + 0]);
            r[4 * j + 1] = fmaf(ekk, tv.y, r[4 * j + 1]);
            r[4 * j + 2] = fmaf(ekk, tv.z, r[4 * j + 2]);
            r[4 * j + 3] = fmaf(ekk, tv.w, r[4 * j + 3]);
        }
    }
#pragma unroll
    for (int q = 0; q < 32; ++q) e[q] = r[q];
}

// 32 blocks (one per chain) x 512 threads (8 waves). All cross-phase deps are block-local
// __syncthreads(); T/E/W round-trip through this block's own L2 (same CU, store->L2, L1
// invalidated by own stores) — no cross-XCD coherence dependence.
__global__ __launch_bounds__(512, 2) void scan_fused(const float* __restrict__ hs,
                                                     const float* __restrict__ Wup,
                                                     const float* __restrict__ Wdn,
                                                     float* __restrict__ Ttot,
                                                     float* __restrict__ Eexc,
                                                     float* __restrict__ Wkp,
                                                     bf16* __restrict__ down,
                                                     float* __restrict__ state_out) {
    __shared__ float Ush[8][1024];
    int chain = blockIdx.x;                 // 0..31
    int tid = threadIdx.x;
    int wv = __builtin_amdgcn_readfirstlane(tid >> 6);   // 0..7
    int lane = tid & 63;
    int o = lane & 31;
    int b = chain >> 4, head = chain & 15;

    float wq[64];
#pragma unroll
    for (int j = 0; j < 16; ++j) ((float4*)wq)[j] = ((const float4*)Wup)[j];

    // ---------- phase A (pass1): wave wv owns segments wv*8 .. wv*8+7 ----------
    for (int i = 0; i < 8; ++i) {
        int g = wv * 8 + i;
        float p[32];
#pragma unroll
        for (int q = 0; q < 32; ++q) p[q] = (q == o) ? 1.0f : 0.0f;
        const float* hb = hs + ((size_t)chain * Ss + (size_t)g * SEGL) * 64;
        float4 ac[16];
#pragma unroll
        for (int j = 0; j < 16; ++j) ac[j] = ((const float4*)hb)[j];
        for (int st = 0; st < SEGL; ++st) {
            float4 an[16];
            if (st + 1 < SEGL) {
                const float4* hn = (const float4*)(hb + (size_t)(st + 1) * 64);
#pragma unroll
                for (int j = 0; j < 16; ++j) an[j] = hn[j];
            }
            float s0 = 0.f, s1 = 0.f, u0 = 0.f, u1 = 0.f;
#pragma unroll
            for (int q = 0; q < 32; q += 2) {
                float4 v = ac[q >> 1];
                s0 = fmaf(p[q], v.x, s0);
                u0 = fmaf(p[q], v.y, u0);
                s1 = fmaf(p[q + 1], v.z, s1);
                u1 = fmaf(p[q + 1], v.w, u1);
            }
            float y0 = s0 + s1, y1 = u0 + u1;
#pragma unroll
            for (int q = 0; q < 32; ++q) p[q] = fmaf(y0, wq[2 * q], fmaf(y1, wq[2 * q + 1], p[q]));
            if (st + 1 < SEGL) {
#pragma unroll
                for (int j = 0; j < 16; ++j) ac[j] = an[j];
            }
        }
        if (lane < 32) {
            float* tb = Ttot + ((size_t)chain * NSEG + g) * 1024 + o * 32;
#pragma unroll
            for (int j = 0; j < 8; ++j)
                ((float4*)tb)[j] = make_float4(p[4 * j], p[4 * j + 1], p[4 * j + 2], p[4 * j + 3]);
        }
    }
    __syncthreads();

    // ---------- phase B (pass2): wave k owns group k ----------
    {
        int k = wv;
        float e[32];
#pragma unroll
        for (int q = 0; q < 32; ++q) e[q] = (q == o) ? 1.0f : 0.0f;
        for (int i = 0; i < GRPL; ++i) {
            int g = k * GRPL + i;
            if (lane < 32) {
                float* eb = Eexc + ((size_t)chain * NSEG + g) * 1024 + o * 32;
#pragma unroll
                for (int j = 0; j < 8; ++j)
                    ((float4*)eb)[j] = make_float4(e[4 * j], e[4 * j + 1], e[4 * j + 2], e[4 * j + 3]);
            }
            row_matmul(e, Ttot + ((size_t)chain * NSEG + g) * 1024);
        }
        if (lane < 32) {
            float* ub = &Ush[k][o * 32];
#pragma unroll
            for (int j = 0; j < 8; ++j)
                ((float4*)ub)[j] = make_float4(e[4 * j], e[4 * j + 1], e[4 * j + 2], e[4 * j + 3]);
        }
        __syncthreads();
        float wreg[32];
#pragma unroll
        for (int q = 0; q < 32; ++q) wreg[q] = (q == o) ? 1.0f : 0.0f;
        for (int j = 0; j < k; ++j) row_matmul(wreg, &Ush[j][0]);
        if (lane < 32) {
            float* wb = Wkp + ((size_t)chain * NGRP + k) * 1024 + o * 32;
#pragma unroll
            for (int j = 0; j < 8; ++j)
                ((float4*)wb)[j] = make_float4(wreg[4 * j], wreg[4 * j + 1], wreg[4 * j + 2], wreg[4 * j + 3]);
        }
    }
    __syncthreads();

    // ---------- phase C (pass3): wave wv owns segments wv*8 .. wv*8+7 ----------
    float wd[64];
#pragma unroll
    for (int j = 0; j < 16; ++j) ((float4*)wd)[j] = ((const float4*)Wdn)[j];
    float G00 = 0.f, G01 = 0.f, G10 = 0.f, G11 = 0.f;
#pragma unroll
    for (int q = 0; q < 32; ++q) {
        G00 = fmaf(wq[2 * q + 0], wd[q], G00);
        G01 = fmaf(wq[2 * q + 0], wd[32 + q], G01);
        G10 = fmaf(wq[2 * q + 1], wd[q], G10);
        G11 = fmaf(wq[2 * q + 1], wd[32 + q], G11);
    }

    for (int i = 0; i < 8; ++i) {
        int g = wv * 8 + i;
        int k = g >> 3;                     // == wv

        float wrow[32];
        const float* wb = Wkp + ((size_t)chain * NGRP + k) * 1024 + o * 32;
#pragma unroll
        for (int j = 0; j < 8; ++j) ((float4*)wrow)[j] = ((const float4*)wb)[j];
        const float* Eb = Eexc + ((size_t)chain * NSEG + g) * 1024;
        float p[32];
#pragma unroll
        for (int q = 0; q < 32; ++q) p[q] = 0.f;
#pragma unroll
        for (int kk = 0; kk < 32; ++kk) {
            float wkk = wrow[kk];
            const float4* er = (const float4*)(Eb + kk * 32);
#pragma unroll
            for (int j = 0; j < 8; ++j) {
                float4 ev = er[j];
                p[4 * j + 0] = fmaf(wkk, ev.x, p[4 * j + 0]);
                p[4 * j + 1] = fmaf(wkk, ev.y, p[4 * j + 1]);
                p[4 * j + 2] = fmaf(wkk, ev.z, p[4 * j + 2]);
                p[4 * j + 3] = fmaf(wkk, ev.w, p[4 * j + 3]);
            }
        }

        float d0 = 0.f, d1 = 0.f;
#pragma unroll
        for (int q = 0; q < 32; ++q) {
            d0 = fmaf(p[q], wd[q], d0);
            d1 = fmaf(p[q], wd[32 + q], d1);
        }

        const float* hb = hs + ((size_t)chain * Ss + (size_t)g * SEGL) * 64;
        bf16* db = down + ((size_t)b * Ss + (size_t)g * SEGL) * Ee + head * 64 + o * 2;
        float* sb = state_out + ((size_t)g * SEGL * Hh + head) * 1024 + o * 32;

        float4 ac[16];
#pragma unroll
        for (int j = 0; j < 16; ++j) ac[j] = ((const float4*)hb)[j];

        for (int st = 0; st < SEGL; ++st) {
            float4 an[16];
            if (st + 1 < SEGL) {
                const float4* hn = (const float4*)(hb + (size_t)(st + 1) * 64);
#pragma unroll
                for (int j = 0; j < 16; ++j) an[j] = hn[j];
            }
            float s0 = 0.f, s1 = 0.f, u0 = 0.f, u1 = 0.f;
#pragma unroll
            for (int q = 0; q < 32; q += 2) {
                float4 v = ac[q >> 1];
                s0 = fmaf(p[q], v.x, s0);
                u0 = fmaf(p[q], v.y, u0);
                s1 = fmaf(p[q + 1], v.z, s1);
                u1 = fmaf(p[q + 1], v.w, u1);
            }
            float y0 = s0 + s1, y1 = u0 + u1;
#pragma unroll
            for (int q = 0; q < 32; ++q) p[q] = fmaf(y0, wq[2 * q], fmaf(y1, wq[2 * q + 1], p[q]));
            d0 = fmaf(y0, G00, fmaf(y1, G10, d0));
            d1 = fmaf(y0, G01, fmaf(y1, G11, d1));
            if (lane < 32) {
                __hip_bfloat162 dv;
                dv.x = __float2bfloat16(d0);
                dv.y = __float2bfloat16(d1);
                *(__hip_bfloat162*)(db + (size_t)st * Ee) = dv;
                if (b == Bb - 1) {
                    float* sp = sb + (size_t)st * (Hh * 1024);
#pragma unroll
                    for (int j = 0; j < 8; ++j)
                        ((float4*)sp)[j] = make_float4(p[4 * j], p[4 * j + 1], p[4 * j + 2], p[4 * j + 3]);
                }
            }
            if (st + 1 < SEGL) {
#pragma unroll
                for (int j = 0; j < 16; ++j) ac[j] = an[j];
            }
        }
    }
}

__device__ __forceinline__ void load_lds16(const bf16* g, short* l) {
    __builtin_amdgcn_global_load_lds((const __attribute__((address_space(1))) unsigned int*)g,
                                     (__attribute__((address_space(3))) unsigned int*)l,
                                     16, 0, 0);
}

// ===== mgemm64: 64x128 tile, 4 waves (32x64 each), BK=32, 3-deep counted-vmcnt (mru & mlp2) =====
template <bool GELU, bool RESID, bool BF16OUT>
__global__ __launch_bounds__(256, 2) void mgemm64(const bf16* __restrict__ A,
                                                  const bf16* __restrict__ Wt,
                                                  const float* __restrict__ res,
                                                  float* __restrict__ Cf,
                                                  bf16* __restrict__ Cb,
                                                  int M, int N, int K) {
    __shared__ __align__(16) short As[3][64 * 32];
    __shared__ __align__(16) short Bs[3][128 * 32];
    int tid = threadIdx.x;
    int w = __builtin_amdgcn_readfirstlane(tid >> 6);
    int l = tid & 63;

    int nbm = M >> 6, nbn = N >> 7;
    int nwg = nbm * nbn;
    int cpx = nwg >> 3;
    int v = ((int)blockIdx.x & 7) * cpx + ((int)blockIdx.x >> 3);
    int sq = v >> 6, rem = v & 63;
    int sqPerRow = nbn >> 3;
    int bm = (sq / sqPerRow) * 8 + (rem >> 3);
    int bn = (sq % sqPerRow) * 8 + (rem & 7);

    int wr = w >> 1, wc = w & 1;
    int lr = l & 15;
    int lks = (((l >> 4) ^ ((lr >> 1) & 3)) * 8);

    int srow = tid >> 2;
    int scol = ((tid & 3) ^ ((tid >> 3) & 3)) * 8;
    const bf16* ga  = A + (size_t)(bm * 64 + srow) * K + scol;
    const bf16* gb0 = Wt + (size_t)(bn * 128 + srow) * K + scol;
    const bf16* gb1 = Wt + (size_t)(bn * 128 + 64 + srow) * K + scol;

    f32x4 acc[2][4];
#pragma unroll
    for (int m = 0; m < 2; ++m)
#pragma unroll
        for (int n = 0; n < 4; ++n) acc[m][n] = (f32x4){0.f, 0.f, 0.f, 0.f};

#define STAGE64(d, kt)                                       \
    do {                                                     \
        int _off = (kt) * 32;                                \
        load_lds16(ga + _off, &As[d][w * 512]);              \
        load_lds16(gb0 + _off, &Bs[d][w * 512]);             \
        load_lds16(gb1 + _off, &Bs[d][2048 + w * 512]);      \
    } while (0)

    const int NK = K >> 5;
    STAGE64(0, 0);
    STAGE64(1, 1);
    STAGE64(2, 2);
    asm volatile("s_waitcnt vmcnt(6)" ::: "memory");
    __builtin_amdgcn_sched_barrier(0);
    __builtin_amdgcn_s_barrier();

    for (int t = 0; t < NK; ++t) {
        int d = t % 3;
        short8 af[2], bfr[4];
#pragma unroll
        for (int m = 0; m < 2; ++m)
            af[m] = *(const short8*)&As[d][(wr * 32 + m * 16 + lr) * 32 + lks];
#pragma unroll
        for (int n = 0; n < 4; ++n)
            bfr[n] = *(const short8*)&Bs[d][(wc * 64 + n * 16 + lr) * 32 + lks];
        asm volatile("s_waitcnt lgkmcnt(0)" ::: "memory");
        __builtin_amdgcn_sched_barrier(0);
        __builtin_amdgcn_s_barrier();
        if (t + 3 < NK) STAGE64(d, t + 3);
        __builtin_amdgcn_sched_barrier(0);
        __builtin_amdgcn_s_setprio(1);
#pragma unroll
        for (int m = 0; m < 2; ++m)
#pragma unroll
            for (int n = 0; n < 4; ++n)
                acc[m][n] = __builtin_amdgcn_mfma_f32_16x16x32_bf16(af[m], bfr[n], acc[m][n], 0, 0, 0);
        __builtin_amdgcn_s_setprio(0);
        if (t + 3 < NK) {
            asm volatile("s_waitcnt vmcnt(6)" ::: "memory");
        } else if (t + 2 < NK) {
            asm volatile("s_waitcnt vmcnt(3)" ::: "memory");
        } else if (t + 1 < NK) {
            asm volatile("s_waitcnt vmcnt(0)" ::: "memory");
        }
        __builtin_amdgcn_sched_barrier(0);
        __builtin_amdgcn_s_barrier();
    }
#undef STAGE64

#pragma unroll
    for (int m = 0; m < 2; ++m) {
#pragma unroll
        for (int n = 0; n < 4; ++n) {
            int gr0 = bm * 64 + wr * 32 + m * 16 + (l >> 4) * 4;
            int gc = bn * 128 + wc * 64 + n * 16 + lr;
#pragma unroll
            for (int j = 0; j < 4; ++j) {
                float v2 = acc[m][n][j];
                if (GELU) v2 = 0.5f * v2 * (1.0f + erff(v2 * 0.70710678118654752f));
                if (RESID) v2 += res[(size_t)(gr0 + j) * N + gc];
                if (BF16OUT) Cb[(size_t)(gr0 + j) * N + gc] = __float2bfloat16(v2);
                else Cf[(size_t)(gr0 + j) * N + gc] = v2;
            }
        }
    }
}

// ===== mgemm8 (mlp1): 256x256, BK=32, 4 LDS bufs, counted vmcnt(8), fine 2-phase =====
__global__ __launch_bounds__(512, 1) void mgemm8(const bf16* __restrict__ A,
                                                 const bf16* __restrict__ Wt,
                                                 bf16* __restrict__ Cb,
                                                 int M, int N, int K) {
    __shared__ __align__(16) short As[4][256 * 32];
    __shared__ __align__(16) short Bs[4][256 * 32];
    int tid = threadIdx.x;
    int w = __builtin_amdgcn_readfirstlane(tid >> 6);
    int l = tid & 63;

    int nbm = M >> 8, nbn = N >> 8;
    int nwg = nbm * nbn;
    int cpx = nwg >> 3;
    int v = ((int)blockIdx.x & 7) * cpx + ((int)blockIdx.x >> 3);
    int sq = v >> 6, rem = v & 63;
    int sqPerRow = nbn >> 3;
    int bm = (sq / sqPerRow) * 8 + (rem >> 3);
    int bn = (sq % sqPerRow) * 8 + (rem & 7);

    int wr = w >> 2, wc = w & 3;
    int lr = l & 15;
    int lks = (((l >> 4) ^ ((lr >> 1) & 3)) * 8);

    int srow = tid >> 2;
    int scol = ((tid & 3) ^ ((tid >> 3) & 3)) * 8;
    const bf16* ga0 = A + (size_t)(bm * 256 + srow) * K + scol;
    const bf16* ga1 = A + (size_t)(bm * 256 + 128 + srow) * K + scol;
    const bf16* gb0 = Wt + (size_t)(bn * 256 + srow) * K + scol;
    const bf16* gb1 = Wt + (size_t)(bn * 256 + 128 + srow) * K + scol;

    f32x4 acc[8][4];
#pragma unroll
    for (int m = 0; m < 8; ++m)
#pragma unroll
        for (int n = 0; n < 4; ++n) acc[m][n] = (f32x4){0.f, 0.f, 0.f, 0.f};

#define STAGE_A(d, kt)                                       \
    do {                                                     \
        int _off = (kt) * 32;                                \
        load_lds16(ga0 + _off, &As[d][w * 512]);             \
        load_lds16(ga1 + _off, &As[d][4096 + w * 512]);      \
    } while (0)
#define STAGE_B(d, kt)                                       \
    do {                                                     \
        int _off = (kt) * 32;                                \
        load_lds16(gb0 + _off, &Bs[d][w * 512]);             \
        load_lds16(gb1 + _off, &Bs[d][4096 + w * 512]);      \
    } while (0)

    const int NK = K >> 5;
    STAGE_A(0, 0); STAGE_B(0, 0);
    STAGE_A(1, 1); STAGE_B(1, 1);
    STAGE_A(2, 2); STAGE_B(2, 2);
    asm volatile("s_waitcnt vmcnt(8)" ::: "memory");
    __builtin_amdgcn_sched_barrier(0);
    __builtin_amdgcn_s_barrier();

    for (int t = 0; t < NK; ++t) {
        int d = t & 3;
        short8 af[8], bfr[4];
#pragma unroll
        for (int n = 0; n < 4; ++n)
            bfr[n] = *(const short8*)&Bs[d][(wc * 64 + n * 16 + lr) * 32 + lks];
#pragma unroll
        for (int m = 0; m < 4; ++m)
            af[m] = *(const short8*)&As[d][(wr * 128 + m * 16 + lr) * 32 + lks];
        if (t + 3 < NK) STAGE_A((t + 3) & 3, t + 3);
        __builtin_amdgcn_sched_barrier(0);
        __builtin_amdgcn_s_barrier();
        asm volatile("s_waitcnt lgkmcnt(0)" ::: "memory");
        __builtin_amdgcn_sched_barrier(0);
        __builtin_amdgcn_s_setprio(1);
#pragma unroll
        for (int m = 0; m < 4; ++m)
#pragma unroll
            for (int n = 0; n < 4; ++n)
                acc[m][n] = __builtin_amdgcn_mfma_f32_16x16x32_bf16(af[m], bfr[n], acc[m][n], 0, 0, 0);
        __builtin_amdgcn_s_setprio(0);
        __builtin_amdgcn_s_barrier();
#pragma unroll
        for (int m = 4; m < 8; ++m)
            af[m] = *(const short8*)&As[d][(wr * 128 + m * 16 + lr) * 32 + lks];
        if (t + 3 < NK) STAGE_B((t + 3) & 3, t + 3);
        __builtin_amdgcn_sched_barrier(0);
        __builtin_amdgcn_s_barrier();
        asm volatile("s_waitcnt lgkmcnt(0)" ::: "memory");
        __builtin_amdgcn_sched_barrier(0);
        __builtin_amdgcn_s_setprio(1);
#pragma unroll
        for (int m = 4; m < 8; ++m)
#pragma unroll
            for (int n = 0; n < 4; ++n)
                acc[m][n] = __builtin_amdgcn_mfma_f32_16x16x32_bf16(af[m], bfr[n], acc[m][n], 0, 0, 0);
        __builtin_amdgcn_s_setprio(0);
        if (t + 3 < NK) {
            asm volatile("s_waitcnt vmcnt(8)" ::: "memory");
        } else if (t + 2 < NK) {
            asm volatile("s_waitcnt vmcnt(4)" ::: "memory");
        } else if (t + 1 < NK) {
            asm volatile("s_waitcnt vmcnt(0)" ::: "memory");
        }
        __builtin_amdgcn_sched_barrier(0);
        __builtin_amdgcn_s_barrier();
    }
#undef STAGE_A
#undef STAGE_B

#pragma unroll
    for (int m = 0; m < 8; ++m) {
#pragma unroll
        for (int n = 0; n < 4; ++n) {
            int gr0 = bm * 256 + wr * 128 + m * 16 + (l >> 4) * 4;
            int gc = bn * 256 + wc * 64 + n * 16 + lr;
#pragma unroll
            for (int j = 0; j < 4; ++j) {
                float vv = acc[m][n][j];
                vv = 0.5f * vv * (1.0f + erff(vv * 0.70710678118654752f));
                Cb[(size_t)(gr0 + j) * N + gc] = __float2bfloat16(vv);
            }
        }
    }
}

extern "C" void kernel_launch(void* const* d_in, const int* in_sizes, int n_in,
                              void* d_out, int out_size, void* d_ws, size_t ws_size,
                              hipStream_t stream) {
    const float* act    = (const float*)d_in[0];
    const float* W_up   = (const float*)d_in[1];
    const float* W_down = (const float*)d_in[2];
    const float* W_mru  = (const float*)d_in[3];
    const float* g_ln1  = (const float*)d_in[4];
    const float* g_ln2  = (const float*)d_in[5];
    const float* W_mlp1 = (const float*)d_in[6];
    const float* W_mlp2 = (const float*)d_in[7];

    float* out_x     = (float*)d_out;
    float* out_state = (float*)d_out + (size_t)Bb * Ss * Ee;

    float* wsf = (float*)d_ws;
    const size_t Mfl = 1024 * 1024;
    float* hs       = wsf;
    bf16*  down_bf  = (bf16*)(wsf + 4 * Mfl);
    bf16*  y_bf     = (bf16*)(wsf + 6 * Mfl);
    bf16*  t1_bf    = (bf16*)(wsf + 8 * Mfl);
    float* Ttot = wsf + 8 * Mfl;                    // overlaps t1 (dead before t1 written)
    float* Eexc = wsf + 10 * Mfl;
    float* Wkp  = wsf + 12 * Mfl;
    bf16*  Wmru_bf  = (bf16*)(wsf + 16 * Mfl);
    bf16*  Wmlp1_bf = (bf16*)(wsf + 17 * Mfl);
    bf16*  Wmlp2_bf = (bf16*)(wsf + 19 * Mfl);

    const int MT = Bb * Ss;   // 4096

    prep_kernel<<<MT + 9216, 256, 0, stream>>>(act, g_ln1, hs,
                                               W_mru, Wmru_bf, W_mlp1, Wmlp1_bf, W_mlp2, Wmlp2_bf);
    scan_fused<<<32, 512, 0, stream>>>(hs, W_up, W_down, Ttot, Eexc, Wkp, down_bf, out_state);
    mgemm64<false, true, false><<<(MT / 64) * (Ee / 128), 256, 0, stream>>>(
        down_bf, Wmru_bf, act, out_x, nullptr, MT, Ee, Ee);
    ln_kernel<bf16><<<MT, 256, 0, stream>>>(out_x, g_ln2, y_bf);
    mgemm8<<<(MT / 256) * (4 * Ee / 256), 512, 0, stream>>>(
        y_bf, Wmlp1_bf, t1_bf, MT, 4 * Ee, Ee);
    mgemm64<false, true, false><<<(MT / 64) * (Ee / 128), 256, 0, stream>>>(
        t1_bf, Wmlp2_bf, out_x, out_x, nullptr, MT, Ee, 4 * Ee);
}

// Round 17
// 337.765 us; speedup vs baseline: 3.4596x; 3.4596x over previous
//
#include <hip/hip_runtime.h>
#include <hip/hip_bf16.h>
#include <math.h>

#define Bb 2
#define Ss 2048
#define Ee 1024
#define Hh 16
#define Oo 32
#define Cc 2
#define EPSf 1e-5f
#define NSEG 64
#define SEGL 32
#define NGRP 8
#define GRPL 8

typedef __hip_bfloat16 bf16;
typedef __attribute__((ext_vector_type(8))) short short8;
typedef __attribute__((ext_vector_type(4))) float f32x4;

// ---------------- LayerNorm (standard layout; used for LN2 only) ----------------
template <typename OT>
__global__ __launch_bounds__(256) void ln_kernel(const float* __restrict__ x,
                                                 const float* __restrict__ g,
                                                 OT* __restrict__ out) {
    __shared__ float red[8];
    int row = blockIdx.x;
    const float4* xr = (const float4*)(x + (size_t)row * Ee);
    float4 v = xr[threadIdx.x];
    float s = v.x + v.y + v.z + v.w;
#pragma unroll
    for (int off = 32; off > 0; off >>= 1) s += __shfl_xor(s, off);
    int wave = threadIdx.x >> 6, lane = threadIdx.x & 63;
    if (!lane) red[wave] = s;
    __syncthreads();
    float mu = (red[0] + red[1] + red[2] + red[3]) * (1.0f / Ee);
    float dx = v.x - mu, dy = v.y - mu, dz = v.z - mu, dw = v.w - mu;
    float sq = dx * dx + dy * dy + dz * dz + dw * dw;
#pragma unroll
    for (int off = 32; off > 0; off >>= 1) sq += __shfl_xor(sq, off);
    if (!lane) red[wave + 4] = sq;
    __syncthreads();
    float var = (red[4] + red[5] + red[6] + red[7]) * (1.0f / Ee);
    float rs = rsqrtf(var + EPSf);
    float4 gv = ((const float4*)g)[threadIdx.x];
    float o0 = dx * rs * gv.x, o1 = dy * rs * gv.y, o2 = dz * rs * gv.z, o3 = dw * rs * gv.w;
    if constexpr (sizeof(OT) == 4) {
        ((float4*)((float*)out + (size_t)row * Ee))[threadIdx.x] = make_float4(o0, o1, o2, o3);
    } else {
        __align__(8) bf16 t[4] = {__float2bfloat16(o0), __float2bfloat16(o1),
                                  __float2bfloat16(o2), __float2bfloat16(o3)};
        ((ushort4*)((unsigned short*)out + (size_t)row * Ee))[threadIdx.x] = *(const ushort4*)t;
    }
}

// ---------------- fused prep: LN1 (chain-major out) + weight f2bf conversions ----------------
__device__ __forceinline__ void cvt4(const float* in, bf16* out, int i) {
    float4 v = ((const float4*)in)[i];
    __align__(8) bf16 t[4] = {__float2bfloat16(v.x), __float2bfloat16(v.y),
                              __float2bfloat16(v.z), __float2bfloat16(v.w)};
    ((ushort4*)out)[i] = *(const ushort4*)t;
}

__global__ __launch_bounds__(256) void prep_kernel(const float* __restrict__ act,
                                                   const float* __restrict__ g,
                                                   float* __restrict__ hs,
                                                   const float* __restrict__ wa, bf16* __restrict__ oa,
                                                   const float* __restrict__ wb, bf16* __restrict__ ob,
                                                   const float* __restrict__ wc, bf16* __restrict__ oc) {
    int bid = blockIdx.x;
    if (bid < Bb * Ss) {
        __shared__ float red[8];
        int row = bid;
        const float4* xr = (const float4*)(act + (size_t)row * Ee);
        float4 v = xr[threadIdx.x];
        float s = v.x + v.y + v.z + v.w;
#pragma unroll
        for (int off = 32; off > 0; off >>= 1) s += __shfl_xor(s, off);
        int wave = threadIdx.x >> 6, lane = threadIdx.x & 63;
        if (!lane) red[wave] = s;
        __syncthreads();
        float mu = (red[0] + red[1] + red[2] + red[3]) * (1.0f / Ee);
        float dx = v.x - mu, dy = v.y - mu, dz = v.z - mu, dw = v.w - mu;
        float sq = dx * dx + dy * dy + dz * dz + dw * dw;
#pragma unroll
        for (int off = 32; off > 0; off >>= 1) sq += __shfl_xor(sq, off);
        if (!lane) red[wave + 4] = sq;
        __syncthreads();
        float var = (red[4] + red[5] + red[6] + red[7]) * (1.0f / Ee);
        float rs = rsqrtf(var + EPSf);
        float4 gv = ((const float4*)g)[threadIdx.x];
        float o0 = dx * rs * gv.x, o1 = dy * rs * gv.y, o2 = dz * rs * gv.z, o3 = dw * rs * gv.w;
        int b = row >> 11, t = row & 2047;
        int e0 = threadIdx.x * 4;
        int head = e0 >> 6;
        float* dst = hs + (((size_t)(b * Hh + head) * Ss) + t) * 64 + (e0 & 63);
        *(float4*)dst = make_float4(o0, o1, o2, o3);
    } else {
        int i = (bid - Bb * Ss) * 256 + threadIdx.x;
        const int nA = (1024 * 1024) / 4;
        const int nB = (4 * 1024 * 1024) / 4;
        if (i < nA) cvt4(wa, oa, i);
        else if (i < nA + nB) cvt4(wb, ob, i - nA);
        else cvt4(wc, oc, i - nA - nB);
    }
}

// ======================= Segmented scan =======================
__device__ __forceinline__ void row_matmul(float e[32], const float* __restrict__ T) {
    float r[32];
#pragma unroll
    for (int q = 0; q < 32; ++q) r[q] = 0.f;
#pragma unroll
    for (int kk = 0; kk < 32; ++kk) {
        float ekk = e[kk];
        const float4* tr = (const float4*)(T + kk * 32);
#pragma unroll
        for (int j = 0; j < 8; ++j) {
            float4 tv = tr[j];
            r[4 * j + 0] = fmaf(ekk, tv.x, r[4 * j + 0]);
            r[4 * j + 1] = fmaf(ekk, tv.y, r[4 * j + 1]);
            r[4 * j + 2] = fmaf(ekk, tv.z, r[4 * j + 2]);
            r[4 * j + 3] = fmaf(ekk, tv.w, r[4 * j + 3]);
        }
    }
#pragma unroll
    for (int q = 0; q < 32; ++q) e[q] = r[q];
}

__global__ __launch_bounds__(256, 2) void scan_pass1(const float* __restrict__ hs,
                                                     const float* __restrict__ Wup,
                                                     float* __restrict__ Ttot) {
    int wv = __builtin_amdgcn_readfirstlane((int)(threadIdx.x >> 6));
    int lane = threadIdx.x & 63;
    int o = lane & 31;
    int seg = blockIdx.x * 4 + wv;
    int chain = seg >> 6;
    int g = seg & 63;

    float wq[64];
#pragma unroll
    for (int j = 0; j < 16; ++j) ((float4*)wq)[j] = ((const float4*)Wup)[j];
    float p[32];
#pragma unroll
    for (int q = 0; q < 32; ++q) p[q] = (q == o) ? 1.0f : 0.0f;

    const float* hb = hs + ((size_t)chain * Ss + (size_t)g * SEGL) * 64;
    float4 ac[16];
#pragma unroll
    for (int j = 0; j < 16; ++j) ac[j] = ((const float4*)hb)[j];

    for (int st = 0; st < SEGL; ++st) {
        float4 an[16];
        if (st + 1 < SEGL) {
            const float4* hn = (const float4*)(hb + (size_t)(st + 1) * 64);
#pragma unroll
            for (int j = 0; j < 16; ++j) an[j] = hn[j];
        }
        float s0 = 0.f, s1 = 0.f, u0 = 0.f, u1 = 0.f;
#pragma unroll
        for (int q = 0; q < 32; q += 2) {
            float4 v = ac[q >> 1];
            s0 = fmaf(p[q], v.x, s0);
            u0 = fmaf(p[q], v.y, u0);
            s1 = fmaf(p[q + 1], v.z, s1);
            u1 = fmaf(p[q + 1], v.w, u1);
        }
        float y0 = s0 + s1, y1 = u0 + u1;
#pragma unroll
        for (int q = 0; q < 32; ++q) p[q] = fmaf(y0, wq[2 * q], fmaf(y1, wq[2 * q + 1], p[q]));
        if (st + 1 < SEGL) {
#pragma unroll
            for (int j = 0; j < 16; ++j) ac[j] = an[j];
        }
    }
    if (lane < 32) {
        float* tb = Ttot + ((size_t)chain * NSEG + g) * 1024 + o * 32;
#pragma unroll
        for (int j = 0; j < 8; ++j)
            ((float4*)tb)[j] = make_float4(p[4 * j], p[4 * j + 1], p[4 * j + 2], p[4 * j + 3]);
    }
}

__global__ __launch_bounds__(512) void scan_pass2(const float* __restrict__ Ttot,
                                                  float* __restrict__ Eexc,
                                                  float* __restrict__ Wkp) {
    __shared__ float Ush[8][1024];
    int chain = blockIdx.x;
    int k = __builtin_amdgcn_readfirstlane((int)(threadIdx.x >> 6));
    int lane = threadIdx.x & 63;
    int o = lane & 31;

    float e[32];
#pragma unroll
    for (int q = 0; q < 32; ++q) e[q] = (q == o) ? 1.0f : 0.0f;
    for (int i = 0; i < GRPL; ++i) {
        int g = k * GRPL + i;
        if (lane < 32) {
            float* eb = Eexc + ((size_t)chain * NSEG + g) * 1024 + o * 32;
#pragma unroll
            for (int j = 0; j < 8; ++j)
                ((float4*)eb)[j] = make_float4(e[4 * j], e[4 * j + 1], e[4 * j + 2], e[4 * j + 3]);
        }
        row_matmul(e, Ttot + ((size_t)chain * NSEG + g) * 1024);
    }
    if (lane < 32) {
        float* ub = &Ush[k][o * 32];
#pragma unroll
        for (int j = 0; j < 8; ++j)
            ((float4*)ub)[j] = make_float4(e[4 * j], e[4 * j + 1], e[4 * j + 2], e[4 * j + 3]);
    }
    __syncthreads();
    float wreg[32];
#pragma unroll
    for (int q = 0; q < 32; ++q) wreg[q] = (q == o) ? 1.0f : 0.0f;
    for (int j = 0; j < k; ++j) row_matmul(wreg, &Ush[j][0]);
    if (lane < 32) {
        float* wb = Wkp + ((size_t)chain * NGRP + k) * 1024 + o * 32;
#pragma unroll
        for (int j = 0; j < 8; ++j)
            ((float4*)wb)[j] = make_float4(wreg[4 * j], wreg[4 * j + 1], wreg[4 * j + 2], wreg[4 * j + 3]);
    }
}

__global__ __launch_bounds__(256, 2) void scan_pass3(const float* __restrict__ hs,
                                                     const float* __restrict__ Wup,
                                                     const float* __restrict__ Wdn,
                                                     const float* __restrict__ Eexc,
                                                     const float* __restrict__ Wkp,
                                                     bf16* __restrict__ down,
                                                     float* __restrict__ state_out) {
    int wv = __builtin_amdgcn_readfirstlane((int)(threadIdx.x >> 6));
    int lane = threadIdx.x & 63;
    int o = lane & 31;
    int seg = blockIdx.x * 4 + wv;
    int chain = seg >> 6;
    int g = seg & 63;
    int b = chain >> 4, head = chain & 15;
    int k = g >> 3;

    float wq[64];
#pragma unroll
    for (int j = 0; j < 16; ++j) ((float4*)wq)[j] = ((const float4*)Wup)[j];
    float wd[64];
#pragma unroll
    for (int j = 0; j < 16; ++j) ((float4*)wd)[j] = ((const float4*)Wdn)[j];

    float G00 = 0.f, G01 = 0.f, G10 = 0.f, G11 = 0.f;
#pragma unroll
    for (int q = 0; q < 32; ++q) {
        G00 = fmaf(wq[2 * q + 0], wd[q], G00);
        G01 = fmaf(wq[2 * q + 0], wd[32 + q], G01);
        G10 = fmaf(wq[2 * q + 1], wd[q], G10);
        G11 = fmaf(wq[2 * q + 1], wd[32 + q], G11);
    }

    float wrow[32];
    const float* wb = Wkp + ((size_t)chain * NGRP + k) * 1024 + o * 32;
#pragma unroll
    for (int j = 0; j < 8; ++j) ((float4*)wrow)[j] = ((const float4*)wb)[j];
    const float* Eb = Eexc + ((size_t)chain * NSEG + g) * 1024;
    float p[32];
#pragma unroll
    for (int q = 0; q < 32; ++q) p[q] = 0.f;
#pragma unroll
    for (int kk = 0; kk < 32; ++kk) {
        float wkk = wrow[kk];
        const float4* er = (const float4*)(Eb + kk * 32);
#pragma unroll
        for (int j = 0; j < 8; ++j) {
            float4 ev = er[j];
            p[4 * j + 0] = fmaf(wkk, ev.x, p[4 * j + 0]);
            p[4 * j + 1] = fmaf(wkk, ev.y, p[4 * j + 1]);
            p[4 * j + 2] = fmaf(wkk, ev.z, p[4 * j + 2]);
            p[4 * j + 3] = fmaf(wkk, ev.w, p[4 * j + 3]);
        }
    }

    float d0 = 0.f, d1 = 0.f;
#pragma unroll
    for (int q = 0; q < 32; ++q) {
        d0 = fmaf(p[q], wd[q], d0);
        d1 = fmaf(p[q], wd[32 + q], d1);
    }

    const float* hb = hs + ((size_t)chain * Ss + (size_t)g * SEGL) * 64;
    bf16* db = down + ((size_t)b * Ss + (size_t)g * SEGL) * Ee + head * 64 + o * 2;
    float* sb = state_out + ((size_t)g * SEGL * Hh + head) * 1024 + o * 32;

    float4 ac[16];
#pragma unroll
    for (int j = 0; j < 16; ++j) ac[j] = ((const float4*)hb)[j];

    for (int st = 0; st < SEGL; ++st) {
        float4 an[16];
        if (st + 1 < SEGL) {
            const float4* hn = (const float4*)(hb + (size_t)(st + 1) * 64);
#pragma unroll
            for (int j = 0; j < 16; ++j) an[j] = hn[j];
        }
        float s0 = 0.f, s1 = 0.f, u0 = 0.f, u1 = 0.f;
#pragma unroll
        for (int q = 0; q < 32; q += 2) {
            float4 v = ac[q >> 1];
            s0 = fmaf(p[q], v.x, s0);
            u0 = fmaf(p[q], v.y, u0);
            s1 = fmaf(p[q + 1], v.z, s1);
            u1 = fmaf(p[q + 1], v.w, u1);
        }
        float y0 = s0 + s1, y1 = u0 + u1;
#pragma unroll
        for (int q = 0; q < 32; ++q) p[q] = fmaf(y0, wq[2 * q], fmaf(y1, wq[2 * q + 1], p[q]));
        d0 = fmaf(y0, G00, fmaf(y1, G10, d0));
        d1 = fmaf(y0, G01, fmaf(y1, G11, d1));
        if (lane < 32) {
            __hip_bfloat162 dv;
            dv.x = __float2bfloat16(d0);
            dv.y = __float2bfloat16(d1);
            *(__hip_bfloat162*)(db + (size_t)st * Ee) = dv;
            if (b == Bb - 1) {
                float* sp = sb + (size_t)st * (Hh * 1024);
#pragma unroll
                for (int j = 0; j < 8; ++j)
                    ((float4*)sp)[j] = make_float4(p[4 * j], p[4 * j + 1], p[4 * j + 2], p[4 * j + 3]);
            }
        }
        if (st + 1 < SEGL) {
#pragma unroll
            for (int j = 0; j < 16; ++j) ac[j] = an[j];
        }
    }
}

__device__ __forceinline__ void load_lds16(const bf16* g, short* l) {
    __builtin_amdgcn_global_load_lds((const __attribute__((address_space(1))) unsigned int*)g,
                                     (__attribute__((address_space(3))) unsigned int*)l,
                                     16, 0, 0);
}

// ===== mgemm64: 64x128 tile, 4 waves (32x64 each), BK=32, 3-deep counted-vmcnt (mru & mlp2) =====
template <bool GELU, bool RESID, bool BF16OUT>
__global__ __launch_bounds__(256, 2) void mgemm64(const bf16* __restrict__ A,
                                                  const bf16* __restrict__ Wt,
                                                  const float* __restrict__ res,
                                                  float* __restrict__ Cf,
                                                  bf16* __restrict__ Cb,
                                                  int M, int N, int K) {
    __shared__ __align__(16) short As[3][64 * 32];
    __shared__ __align__(16) short Bs[3][128 * 32];
    int tid = threadIdx.x;
    int w = __builtin_amdgcn_readfirstlane(tid >> 6);
    int l = tid & 63;

    int nbm = M >> 6, nbn = N >> 7;
    int nwg = nbm * nbn;
    int cpx = nwg >> 3;
    int v = ((int)blockIdx.x & 7) * cpx + ((int)blockIdx.x >> 3);
    int sq = v >> 6, rem = v & 63;
    int sqPerRow = nbn >> 3;
    int bm = (sq / sqPerRow) * 8 + (rem >> 3);
    int bn = (sq % sqPerRow) * 8 + (rem & 7);

    int wr = w >> 1, wc = w & 1;
    int lr = l & 15;
    int lks = (((l >> 4) ^ ((lr >> 1) & 3)) * 8);

    int srow = tid >> 2;
    int scol = ((tid & 3) ^ ((tid >> 3) & 3)) * 8;
    const bf16* ga  = A + (size_t)(bm * 64 + srow) * K + scol;
    const bf16* gb0 = Wt + (size_t)(bn * 128 + srow) * K + scol;
    const bf16* gb1 = Wt + (size_t)(bn * 128 + 64 + srow) * K + scol;

    f32x4 acc[2][4];
#pragma unroll
    for (int m = 0; m < 2; ++m)
#pragma unroll
        for (int n = 0; n < 4; ++n) acc[m][n] = (f32x4){0.f, 0.f, 0.f, 0.f};

#define STAGE64(d, kt)                                       \
    do {                                                     \
        int _off = (kt) * 32;                                \
        load_lds16(ga + _off, &As[d][w * 512]);              \
        load_lds16(gb0 + _off, &Bs[d][w * 512]);             \
        load_lds16(gb1 + _off, &Bs[d][2048 + w * 512]);      \
    } while (0)

    const int NK = K >> 5;
    STAGE64(0, 0);
    STAGE64(1, 1);
    STAGE64(2, 2);
    asm volatile("s_waitcnt vmcnt(6)" ::: "memory");
    __builtin_amdgcn_sched_barrier(0);
    __builtin_amdgcn_s_barrier();

    for (int t = 0; t < NK; ++t) {
        int d = t % 3;
        short8 af[2], bfr[4];
#pragma unroll
        for (int m = 0; m < 2; ++m)
            af[m] = *(const short8*)&As[d][(wr * 32 + m * 16 + lr) * 32 + lks];
#pragma unroll
        for (int n = 0; n < 4; ++n)
            bfr[n] = *(const short8*)&Bs[d][(wc * 64 + n * 16 + lr) * 32 + lks];
        asm volatile("s_waitcnt lgkmcnt(0)" ::: "memory");
        __builtin_amdgcn_sched_barrier(0);
        __builtin_amdgcn_s_barrier();
        if (t + 3 < NK) STAGE64(d, t + 3);
        __builtin_amdgcn_sched_barrier(0);
        __builtin_amdgcn_s_setprio(1);
#pragma unroll
        for (int m = 0; m < 2; ++m)
#pragma unroll
            for (int n = 0; n < 4; ++n)
                acc[m][n] = __builtin_amdgcn_mfma_f32_16x16x32_bf16(af[m], bfr[n], acc[m][n], 0, 0, 0);
        __builtin_amdgcn_s_setprio(0);
        if (t + 3 < NK) {
            asm volatile("s_waitcnt vmcnt(6)" ::: "memory");
        } else if (t + 2 < NK) {
            asm volatile("s_waitcnt vmcnt(3)" ::: "memory");
        } else if (t + 1 < NK) {
            asm volatile("s_waitcnt vmcnt(0)" ::: "memory");
        }
        __builtin_amdgcn_sched_barrier(0);
        __builtin_amdgcn_s_barrier();
    }
#undef STAGE64

#pragma unroll
    for (int m = 0; m < 2; ++m) {
#pragma unroll
        for (int n = 0; n < 4; ++n) {
            int gr0 = bm * 64 + wr * 32 + m * 16 + (l >> 4) * 4;
            int gc = bn * 128 + wc * 64 + n * 16 + lr;
#pragma unroll
            for (int j = 0; j < 4; ++j) {
                float v2 = acc[m][n][j];
                if (GELU) v2 = 0.5f * v2 * (1.0f + erff(v2 * 0.70710678118654752f));
                if (RESID) v2 += res[(size_t)(gr0 + j) * N + gc];
                if (BF16OUT) Cb[(size_t)(gr0 + j) * N + gc] = __float2bfloat16(v2);
                else Cf[(size_t)(gr0 + j) * N + gc] = v2;
            }
        }
    }
}

// ===== mgemm8 (mlp1): 256x256, BK=32, 4 LDS bufs, counted vmcnt(8), fine 2-phase =====
__global__ __launch_bounds__(512, 1) void mgemm8(const bf16* __restrict__ A,
                                                 const bf16* __restrict__ Wt,
                                                 bf16* __restrict__ Cb,
                                                 int M, int N, int K) {
    __shared__ __align__(16) short As[4][256 * 32];
    __shared__ __align__(16) short Bs[4][256 * 32];
    int tid = threadIdx.x;
    int w = __builtin_amdgcn_readfirstlane(tid >> 6);
    int l = tid & 63;

    int nbm = M >> 8, nbn = N >> 8;
    int nwg = nbm * nbn;
    int cpx = nwg >> 3;
    int v = ((int)blockIdx.x & 7) * cpx + ((int)blockIdx.x >> 3);
    int sq = v >> 6, rem = v & 63;
    int sqPerRow = nbn >> 3;
    int bm = (sq / sqPerRow) * 8 + (rem >> 3);
    int bn = (sq % sqPerRow) * 8 + (rem & 7);

    int wr = w >> 2, wc = w & 3;
    int lr = l & 15;
    int lks = (((l >> 4) ^ ((lr >> 1) & 3)) * 8);

    int srow = tid >> 2;
    int scol = ((tid & 3) ^ ((tid >> 3) & 3)) * 8;
    const bf16* ga0 = A + (size_t)(bm * 256 + srow) * K + scol;
    const bf16* ga1 = A + (size_t)(bm * 256 + 128 + srow) * K + scol;
    const bf16* gb0 = Wt + (size_t)(bn * 256 + srow) * K + scol;
    const bf16* gb1 = Wt + (size_t)(bn * 256 + 128 + srow) * K + scol;

    f32x4 acc[8][4];
#pragma unroll
    for (int m = 0; m < 8; ++m)
#pragma unroll
        for (int n = 0; n < 4; ++n) acc[m][n] = (f32x4){0.f, 0.f, 0.f, 0.f};

#define STAGE_A(d, kt)                                       \
    do {                                                     \
        int _off = (kt) * 32;                                \
        load_lds16(ga0 + _off, &As[d][w * 512]);             \
        load_lds16(ga1 + _off, &As[d][4096 + w * 512]);      \
    } while (0)
#define STAGE_B(d, kt)                                       \
    do {                                                     \
        int _off = (kt) * 32;                                \
        load_lds16(gb0 + _off, &Bs[d][w * 512]);             \
        load_lds16(gb1 + _off, &Bs[d][4096 + w * 512]);      \
    } while (0)

    const int NK = K >> 5;
    STAGE_A(0, 0); STAGE_B(0, 0);
    STAGE_A(1, 1); STAGE_B(1, 1);
    STAGE_A(2, 2); STAGE_B(2, 2);
    asm volatile("s_waitcnt vmcnt(8)" ::: "memory");
    __builtin_amdgcn_sched_barrier(0);
    __builtin_amdgcn_s_barrier();

    for (int t = 0; t < NK; ++t) {
        int d = t & 3;
        short8 af[8], bfr[4];
#pragma unroll
        for (int n = 0; n < 4; ++n)
            bfr[n] = *(const short8*)&Bs[d][(wc * 64 + n * 16 + lr) * 32 + lks];
#pragma unroll
        for (int m = 0; m < 4; ++m)
            af[m] = *(const short8*)&As[d][(wr * 128 + m * 16 + lr) * 32 + lks];
        if (t + 3 < NK) STAGE_A((t + 3) & 3, t + 3);
        __builtin_amdgcn_sched_barrier(0);
        __builtin_amdgcn_s_barrier();
        asm volatile("s_waitcnt lgkmcnt(0)" ::: "memory");
        __builtin_amdgcn_sched_barrier(0);
        __builtin_amdgcn_s_setprio(1);
#pragma unroll
        for (int m = 0; m < 4; ++m)
#pragma unroll
            for (int n = 0; n < 4; ++n)
                acc[m][n] = __builtin_amdgcn_mfma_f32_16x16x32_bf16(af[m], bfr[n], acc[m][n], 0, 0, 0);
        __builtin_amdgcn_s_setprio(0);
        __builtin_amdgcn_s_barrier();
#pragma unroll
        for (int m = 4; m < 8; ++m)
            af[m] = *(const short8*)&As[d][(wr * 128 + m * 16 + lr) * 32 + lks];
        if (t + 3 < NK) STAGE_B((t + 3) & 3, t + 3);
        __builtin_amdgcn_sched_barrier(0);
        __builtin_amdgcn_s_barrier();
        asm volatile("s_waitcnt lgkmcnt(0)" ::: "memory");
        __builtin_amdgcn_sched_barrier(0);
        __builtin_amdgcn_s_setprio(1);
#pragma unroll
        for (int m = 4; m < 8; ++m)
#pragma unroll
            for (int n = 0; n < 4; ++n)
                acc[m][n] = __builtin_amdgcn_mfma_f32_16x16x32_bf16(af[m], bfr[n], acc[m][n], 0, 0, 0);
        __builtin_amdgcn_s_setprio(0);
        if (t + 3 < NK) {
            asm volatile("s_waitcnt vmcnt(8)" ::: "memory");
        } else if (t + 2 < NK) {
            asm volatile("s_waitcnt vmcnt(4)" ::: "memory");
        } else if (t + 1 < NK) {
            asm volatile("s_waitcnt vmcnt(0)" ::: "memory");
        }
        __builtin_amdgcn_sched_barrier(0);
        __builtin_amdgcn_s_barrier();
    }
#undef STAGE_A
#undef STAGE_B

#pragma unroll
    for (int m = 0; m < 8; ++m) {
#pragma unroll
        for (int n = 0; n < 4; ++n) {
            int gr0 = bm * 256 + wr * 128 + m * 16 + (l >> 4) * 4;
            int gc = bn * 256 + wc * 64 + n * 16 + lr;
#pragma unroll
            for (int j = 0; j < 4; ++j) {
                float vv = acc[m][n][j];
                vv = 0.5f * vv * (1.0f + erff(vv * 0.70710678118654752f));
                Cb[(size_t)(gr0 + j) * N + gc] = __float2bfloat16(vv);
            }
        }
    }
}

extern "C" void kernel_launch(void* const* d_in, const int* in_sizes, int n_in,
                              void* d_out, int out_size, void* d_ws, size_t ws_size,
                              hipStream_t stream) {
    const float* act    = (const float*)d_in[0];
    const float* W_up   = (const float*)d_in[1];
    const float* W_down = (const float*)d_in[2];
    const float* W_mru  = (const float*)d_in[3];
    const float* g_ln1  = (const float*)d_in[4];
    const float* g_ln2  = (const float*)d_in[5];
    const float* W_mlp1 = (const float*)d_in[6];
    const float* W_mlp2 = (const float*)d_in[7];

    float* out_x     = (float*)d_out;
    float* out_state = (float*)d_out + (size_t)Bb * Ss * Ee;

    float* wsf = (float*)d_ws;
    const size_t Mfl = 1024 * 1024;
    float* hs       = wsf;
    bf16*  down_bf  = (bf16*)(wsf + 4 * Mfl);
    bf16*  y_bf     = (bf16*)(wsf + 6 * Mfl);
    bf16*  t1_bf    = (bf16*)(wsf + 8 * Mfl);
    float* Ttot = wsf + 8 * Mfl;                    // overlaps t1 (dead before t1 written)
    float* Eexc = wsf + 10 * Mfl;
    float* Wkp  = wsf + 12 * Mfl;
    bf16*  Wmru_bf  = (bf16*)(wsf + 16 * Mfl);
    bf16*  Wmlp1_bf = (bf16*)(wsf + 17 * Mfl);
    bf16*  Wmlp2_bf = (bf16*)(wsf + 19 * Mfl);

    const int MT = Bb * Ss;   // 4096

    prep_kernel<<<MT + 9216, 256, 0, stream>>>(act, g_ln1, hs,
                                               W_mru, Wmru_bf, W_mlp1, Wmlp1_bf, W_mlp2, Wmlp2_bf);
    scan_pass1<<<512, 256, 0, stream>>>(hs, W_up, Ttot);
    scan_pass2<<<32, 512, 0, stream>>>(Ttot, Eexc, Wkp);
    scan_pass3<<<512, 256, 0, stream>>>(hs, W_up, W_down, Eexc, Wkp, down_bf, out_state);
    mgemm64<false, true, false><<<(MT / 64) * (Ee / 128), 256, 0, stream>>>(
        down_bf, Wmru_bf, act, out_x, nullptr, MT, Ee, Ee);
    ln_kernel<bf16><<<MT, 256, 0, stream>>>(out_x, g_ln2, y_bf);
    mgemm8<<<(MT / 256) * (4 * Ee / 256), 512, 0, stream>>>(
        y_bf, Wmlp1_bf, t1_bf, MT, 4 * Ee, Ee);
    mgemm64<false, true, false><<<(MT / 64) * (Ee / 128), 256, 0, stream>>>(
        t1_bf, Wmlp2_bf, out_x, out_x, nullptr, MT, Ee, 4 * Ee);
}